// Round 1
// baseline (862.214 us; speedup 1.0000x reference)
//
#include <hip/hip_runtime.h>
#include <cstddef>

#define TT 1024
#define BB 16384
#define LC 32
#define CC (TT / LC)

// tanh via native exp + rcp: tanh(x) = 1 - 2/(e^{2x}+1). |err| ~1e-6, fine vs 4.8e-2.
__device__ __forceinline__ float fast_tanh(float x) {
    float cx = fminf(fmaxf(x, -9.0f), 9.0f);
    float e  = __expf(2.0f * cx);
    return fmaf(-2.0f, __builtin_amdgcn_rcpf(e + 1.0f), 1.0f);
}

// Phase 1: per (chunk c, batch b) run the affine recurrence from zero state,
// store the chunk offset v[c][i][b]  (layout [C][6][B] for coalescing).
__global__ __launch_bounds__(256) void k_phase1(
    const float* __restrict__ targets,
    const float* __restrict__ Wx,
    const float* __restrict__ Wu,
    float* __restrict__ v)
{
    const int b = blockIdx.x * 256 + threadIdx.x;
    const int c = blockIdx.y;
    float wx[6][6], wu[6];
#pragma unroll
    for (int i = 0; i < 6; ++i) {
        wu[i] = Wu[i];
#pragma unroll
        for (int j = 0; j < 6; ++j) wx[i][j] = Wx[i * 6 + j];
    }
    float db[6] = {0.f, 0.f, 0.f, 0.f, 0.f, 0.f};
    const int t0 = c * LC;
#pragma unroll 4
    for (int s = 0; s < LC; ++s) {
        const int t = t0 + s;
        float u = 0.0f;
        if (t > 0) u = targets[(size_t)(t - 1) * BB + b];
        float nd[6];
#pragma unroll
        for (int i = 0; i < 6; ++i) {
            float a = u * wu[i];
#pragma unroll
            for (int j = 0; j < 6; ++j) a = fmaf(db[j], wx[i][j], a);
            nd[i] = a;
        }
#pragma unroll
        for (int i = 0; i < 6; ++i) db[i] = nd[i];
    }
#pragma unroll
    for (int i = 0; i < 6; ++i) v[((size_t)c * 6 + i) * BB + b] = db[i];
}

// Phase 2: per batch b, sequential prefix over the 32 chunks.
// db_start[c+1] = db_start[c] * M + v[c],  M = (Wx^T)^32 (5 squarings).
// In-place: v[c][.][b] is replaced by db_start[c][.][b].
__global__ __launch_bounds__(256) void k_phase2(
    const float* __restrict__ Wx,
    float* __restrict__ v)
{
    const int b = blockIdx.x * 256 + threadIdx.x;
    float M[6][6];
#pragma unroll
    for (int i = 0; i < 6; ++i)
#pragma unroll
        for (int j = 0; j < 6; ++j)
            M[j][i] = Wx[i * 6 + j];  // N = Wx^T in row-vector convention
    for (int it = 0; it < 5; ++it) {
        float P[6][6];
#pragma unroll
        for (int i = 0; i < 6; ++i)
#pragma unroll
            for (int j = 0; j < 6; ++j) {
                float a = 0.0f;
#pragma unroll
                for (int k = 0; k < 6; ++k) a = fmaf(M[i][k], M[k][j], a);
                P[i][j] = a;
            }
#pragma unroll
        for (int i = 0; i < 6; ++i)
#pragma unroll
            for (int j = 0; j < 6; ++j) M[i][j] = P[i][j];
    }
    float db[6] = {0.f, 0.f, 0.f, 0.f, 0.f, 0.f};
    for (int c = 0; c < CC; ++c) {
        float vv[6];
#pragma unroll
        for (int i = 0; i < 6; ++i) {
            const size_t idx = ((size_t)c * 6 + i) * BB + b;
            vv[i] = v[idx];
            v[idx] = db[i];  // overwrite with the start state for chunk c
        }
        float nd[6];
#pragma unroll
        for (int i = 0; i < 6; ++i) {
            float a = vv[i];
#pragma unroll
            for (int j = 0; j < 6; ++j) a = fmaf(db[j], M[j][i], a);
            nd[i] = a;
        }
#pragma unroll
        for (int i = 0; i < 6; ++i) db[i] = nd[i];
    }
}

// Phase 3: per (chunk, b) replay 32 steps from the exact start state with the
// full MLP. Weights register-resident (staged via LDS once). 1 wave/SIMD.
__global__ __launch_bounds__(256, 1) void k_phase3(
    const float* __restrict__ inputs,
    const float* __restrict__ targets,
    const float* __restrict__ Wxg,
    const float* __restrict__ Wug,
    const float* __restrict__ W1g,
    const float* __restrict__ b1g,
    const float* __restrict__ W2g,
    const float* __restrict__ b2g,
    const float* __restrict__ dbs,
    float* __restrict__ out)
{
    __shared__ float sW1[240];
    __shared__ float sWx[36];
    __shared__ float sWu[6];
    __shared__ float sB1[20];
    __shared__ float sW2[20];
    __shared__ float sB2[1];
    const int tid = threadIdx.x;
    if (tid < 240) sW1[tid] = W1g[tid];
    if (tid < 36)  sWx[tid] = Wxg[tid];
    if (tid < 20)  { sB1[tid] = b1g[tid]; sW2[tid] = W2g[tid]; }
    if (tid < 6)   sWu[tid] = Wug[tid];
    if (tid == 0)  sB2[0] = b2g[0];
    __syncthreads();

    const int b = blockIdx.x * 256 + tid;
    const int c = blockIdx.y;

    // Register-resident weights (forced to VGPRs via the LDS round-trip).
    float w1[240];
#pragma unroll
    for (int k = 0; k < 240; ++k) w1[k] = sW1[k];
    float wx[6][6];
#pragma unroll
    for (int i = 0; i < 6; ++i)
#pragma unroll
        for (int j = 0; j < 6; ++j) wx[i][j] = sWx[i * 6 + j];
    float wu[6];
#pragma unroll
    for (int i = 0; i < 6; ++i) wu[i] = sWu[i];
    float vb1[20], vw2[20];
#pragma unroll
    for (int m = 0; m < 20; ++m) { vb1[m] = sB1[m]; vw2[m] = sW2[m]; }
    const float vb2 = sB2[0];

    float db[6];
#pragma unroll
    for (int i = 0; i < 6; ++i) db[i] = dbs[((size_t)c * 6 + i) * BB + b];

    const int t0 = c * LC;
    // Prefetch step 0's inputs.
    float u_cur = (t0 == 0) ? 0.0f : targets[(size_t)(t0 - 1) * BB + b];
    const float2* xp = reinterpret_cast<const float2*>(inputs + ((size_t)t0 * BB + b) * 6);
    float2 x0 = xp[0], x1 = xp[1], x2 = xp[2];

    for (int s = 0; s < LC; ++s) {
        const int t = t0 + s;
        // Prefetch next step (addresses independent of the recurrence).
        float u_nxt = 0.0f;
        float2 n0 = x0, n1 = x1, n2 = x2;
        if (s + 1 < LC) {
            u_nxt = targets[(size_t)t * BB + b];  // (t+1)-1 = t
            const float2* xpn =
                reinterpret_cast<const float2*>(inputs + ((size_t)(t + 1) * BB + b) * 6);
            n0 = xpn[0]; n1 = xpn[1]; n2 = xpn[2];
        }
        // Delay-buffer update: db = db*Wx^T + u*Wu^T
        float nd[6];
#pragma unroll
        for (int i = 0; i < 6; ++i) {
            float a = u_cur * wu[i];
#pragma unroll
            for (int j = 0; j < 6; ++j) a = fmaf(db[j], wx[i][j], a);
            nd[i] = a;
        }
#pragma unroll
        for (int i = 0; i < 6; ++i) db[i] = nd[i];

        const float xv[6] = {x0.x, x0.y, x1.x, x1.y, x2.x, x2.y};
        // MLP: o = b2 + W2 . tanh(W1 [db;x] + b1)
        float o = vb2;
#pragma unroll
        for (int m = 0; m < 20; ++m) {
            float a = vb1[m];
#pragma unroll
            for (int j = 0; j < 6; ++j) a = fmaf(w1[m * 12 + j], db[j], a);
#pragma unroll
            for (int j = 0; j < 6; ++j) a = fmaf(w1[m * 12 + 6 + j], xv[j], a);
            o = fmaf(vw2[m], fast_tanh(a), o);
        }
        out[(size_t)t * BB + b] = o;

        u_cur = u_nxt; x0 = n0; x1 = n1; x2 = n2;
    }
}

extern "C" void kernel_launch(void* const* d_in, const int* in_sizes, int n_in,
                              void* d_out, int out_size, void* d_ws, size_t ws_size,
                              hipStream_t stream) {
    (void)in_sizes; (void)n_in; (void)out_size; (void)ws_size;
    const float* inputs  = (const float*)d_in[0];
    const float* targets = (const float*)d_in[1];
    const float* Wx = (const float*)d_in[2];
    const float* Wu = (const float*)d_in[3];
    const float* W1 = (const float*)d_in[4];
    const float* b1 = (const float*)d_in[5];
    const float* W2 = (const float*)d_in[6];
    const float* b2 = (const float*)d_in[7];
    float* out = (float*)d_out;
    float* v   = (float*)d_ws;  // needs CC*6*BB*4 = 12.6 MB of workspace

    dim3 blk(256);
    dim3 g1(BB / 256, CC);
    hipLaunchKernelGGL(k_phase1, g1, blk, 0, stream, targets, Wx, Wu, v);
    hipLaunchKernelGGL(k_phase2, dim3(BB / 256), blk, 0, stream, Wx, v);
    hipLaunchKernelGGL(k_phase3, g1, blk, 0, stream,
                       inputs, targets, Wx, Wu, W1, b1, W2, b2, v, out);
}

// Round 2
// 821.490 us; speedup vs baseline: 1.0496x; 1.0496x over previous
//
#include <hip/hip_runtime.h>
#include <cstddef>

#define TT 1024
#define BB 16384
#define LC 32
#define CC (TT / LC)

// Padé(7,6) tanh: tanh(x) ~= x(135135 + 17325 s + 378 s^2 + s^3) /
//                           (135135 + 62370 s + 3150 s^2 + 28 s^3),  s = x^2.
// |err| <= 1.2e-4 on the clamped range [-4.97, 4.97]; beyond, saturation err
// <= 1.2e-4. One transcendental (rcp) instead of exp+rcp.
__device__ __forceinline__ float pade_tanh(float x) {
    float cx = fminf(fmaxf(x, -4.97f), 4.97f);
    float s  = cx * cx;
    float n  = cx * fmaf(s, fmaf(s, (s + 378.0f), 17325.0f), 135135.0f);
    float d  = fmaf(s, fmaf(s, fmaf(s, 28.0f, 3150.0f), 62370.0f), 135135.0f);
    return n * __builtin_amdgcn_rcpf(d);
}

// Phase 1: per (chunk c, batch b) run the affine recurrence from zero state,
// store the chunk offset v[c][i][b]  (layout [C][6][B] for coalescing).
__global__ __launch_bounds__(256) void k_phase1(
    const float* __restrict__ targets,
    const float* __restrict__ Wx,
    const float* __restrict__ Wu,
    float* __restrict__ v)
{
    const int b = blockIdx.x * 256 + threadIdx.x;
    const int c = blockIdx.y;
    float wx[6][6], wu[6];
#pragma unroll
    for (int i = 0; i < 6; ++i) {
        wu[i] = Wu[i];
#pragma unroll
        for (int j = 0; j < 6; ++j) wx[i][j] = Wx[i * 6 + j];
    }
    float db[6] = {0.f, 0.f, 0.f, 0.f, 0.f, 0.f};
    const int t0 = c * LC;
#pragma unroll 4
    for (int s = 0; s < LC; ++s) {
        const int t = t0 + s;
        float u = 0.0f;
        if (t > 0) u = targets[(size_t)(t - 1) * BB + b];
        float nd[6];
#pragma unroll
        for (int i = 0; i < 6; ++i) {
            float a = u * wu[i];
#pragma unroll
            for (int j = 0; j < 6; ++j) a = fmaf(db[j], wx[i][j], a);
            nd[i] = a;
        }
#pragma unroll
        for (int i = 0; i < 6; ++i) db[i] = nd[i];
    }
#pragma unroll
    for (int i = 0; i < 6; ++i) v[((size_t)c * 6 + i) * BB + b] = db[i];
}

// Phase 2: per batch b, sequential prefix over the 32 chunks.
// db_start[c+1] = db_start[c] * M + v[c],  M = (Wx^T)^32 (5 squarings).
// In-place: v[c][.][b] is replaced by db_start[c][.][b].
__global__ __launch_bounds__(256) void k_phase2(
    const float* __restrict__ Wx,
    float* __restrict__ v)
{
    const int b = blockIdx.x * 256 + threadIdx.x;
    float M[6][6];
#pragma unroll
    for (int i = 0; i < 6; ++i)
#pragma unroll
        for (int j = 0; j < 6; ++j)
            M[j][i] = Wx[i * 6 + j];  // N = Wx^T in row-vector convention
    for (int it = 0; it < 5; ++it) {
        float P[6][6];
#pragma unroll
        for (int i = 0; i < 6; ++i)
#pragma unroll
            for (int j = 0; j < 6; ++j) {
                float a = 0.0f;
#pragma unroll
                for (int k = 0; k < 6; ++k) a = fmaf(M[i][k], M[k][j], a);
                P[i][j] = a;
            }
#pragma unroll
        for (int i = 0; i < 6; ++i)
#pragma unroll
            for (int j = 0; j < 6; ++j) M[i][j] = P[i][j];
    }
    float db[6] = {0.f, 0.f, 0.f, 0.f, 0.f, 0.f};
    for (int c = 0; c < CC; ++c) {
        float vv[6];
#pragma unroll
        for (int i = 0; i < 6; ++i) {
            const size_t idx = ((size_t)c * 6 + i) * BB + b;
            vv[i] = v[idx];
            v[idx] = db[i];  // overwrite with the start state for chunk c
        }
        float nd[6];
#pragma unroll
        for (int i = 0; i < 6; ++i) {
            float a = vv[i];
#pragma unroll
            for (int j = 0; j < 6; ++j) a = fmaf(db[j], M[j][i], a);
            nd[i] = a;
        }
#pragma unroll
        for (int i = 0; i < 6; ++i) db[i] = nd[i];
    }
}

// Phase 3 v2: lane PAIRS share one (c,b) column; each lane computes 10 of the
// 20 hidden units (pairs (m, m+5) within its half, packed as float2 for
// v_pk_fma_f32). No LDS: uniform weights (Wx,Wu,b2) become s_loads/SGPRs;
// per-half W1/b1/W2 live in ~140 VGPRs -> fits 2 waves/SIMD.
__global__ __launch_bounds__(256, 2) void k_phase3(
    const float* __restrict__ inputs,
    const float* __restrict__ targets,
    const float* __restrict__ Wxg,
    const float* __restrict__ Wug,
    const float* __restrict__ W1g,
    const float* __restrict__ b1g,
    const float* __restrict__ W2g,
    const float* __restrict__ b2g,
    const float* __restrict__ dbs,
    float* __restrict__ out)
{
    const int tid  = threadIdx.x;
    const int half = tid & 1;
    const int b    = blockIdx.x * 128 + (tid >> 1);
    const int c    = blockIdx.y;
    const int m0   = half * 10;

    // Wave-uniform weights -> compiler emits scalar loads into SGPRs.
    float wx[6][6], wu[6];
#pragma unroll
    for (int i = 0; i < 6; ++i) {
        wu[i] = Wug[i];
#pragma unroll
        for (int j = 0; j < 6; ++j) wx[i][j] = Wxg[i * 6 + j];
    }
    const float vb2 = b2g[0];

    // Per-half (lane-dependent) weights: 5 unit-pairs (m0+p, m0+p+5).
    float2 w1p[5][12];
    float2 vb1[5], vw2[5];
#pragma unroll
    for (int p = 0; p < 5; ++p) {
        const int ma = m0 + p, mb = m0 + p + 5;
#pragma unroll
        for (int j = 0; j < 12; ++j) {
            w1p[p][j].x = W1g[ma * 12 + j];
            w1p[p][j].y = W1g[mb * 12 + j];
        }
        vb1[p].x = b1g[ma]; vb1[p].y = b1g[mb];
        vw2[p].x = W2g[ma]; vw2[p].y = W2g[mb];
    }

    float db[6];
#pragma unroll
    for (int i = 0; i < 6; ++i) db[i] = dbs[((size_t)c * 6 + i) * BB + b];

    const int t0 = c * LC;
    // Prefetch step 0's inputs.
    float u_cur = (t0 == 0) ? 0.0f : targets[(size_t)(t0 - 1) * BB + b];
    const float2* xp = reinterpret_cast<const float2*>(inputs + ((size_t)t0 * BB + b) * 6);
    float2 x0 = xp[0], x1 = xp[1], x2 = xp[2];

    for (int s = 0; s < LC; ++s) {
        const int t = t0 + s;
        // Prefetch next step (addresses independent of the recurrence).
        float u_nxt = 0.0f;
        float2 n0 = x0, n1 = x1, n2 = x2;
        if (s + 1 < LC) {
            u_nxt = targets[(size_t)t * BB + b];  // (t+1)-1 = t
            const float2* xpn =
                reinterpret_cast<const float2*>(inputs + ((size_t)(t + 1) * BB + b) * 6);
            n0 = xpn[0]; n1 = xpn[1]; n2 = xpn[2];
        }

        // Delay-buffer update (duplicated in both lanes of the pair).
        float nd[6];
#pragma unroll
        for (int i = 0; i < 6; ++i) {
            float a = u_cur * wu[i];
#pragma unroll
            for (int j = 0; j < 6; ++j) a = fmaf(db[j], wx[i][j], a);
            nd[i] = a;
        }
#pragma unroll
        for (int i = 0; i < 6; ++i) db[i] = nd[i];

        const float ni[12] = {db[0], db[1], db[2], db[3], db[4], db[5],
                              x0.x, x0.y, x1.x, x1.y, x2.x, x2.y};

        // Layer 1 for my 10 units, packed 2-wide -> v_pk_fma_f32.
        float2 acc[5];
#pragma unroll
        for (int p = 0; p < 5; ++p) acc[p] = vb1[p];
#pragma unroll
        for (int j = 0; j < 12; ++j) {
            const float nij = ni[j];
#pragma unroll
            for (int p = 0; p < 5; ++p) {
                acc[p].x = fmaf(w1p[p][j].x, nij, acc[p].x);
                acc[p].y = fmaf(w1p[p][j].y, nij, acc[p].y);
            }
        }

        // tanh + partial output over my 10 units.
        float2 osum = {0.0f, 0.0f};
#pragma unroll
        for (int p = 0; p < 5; ++p) {
            float tx = pade_tanh(acc[p].x);
            float ty = pade_tanh(acc[p].y);
            osum.x = fmaf(vw2[p].x, tx, osum.x);
            osum.y = fmaf(vw2[p].y, ty, osum.y);
        }
        float oh = osum.x + osum.y;
        float o  = oh + __shfl_xor(oh, 1, 64) + vb2;
        if (half == 0) out[(size_t)t * BB + b] = o;

        u_cur = u_nxt; x0 = n0; x1 = n1; x2 = n2;
    }
}

extern "C" void kernel_launch(void* const* d_in, const int* in_sizes, int n_in,
                              void* d_out, int out_size, void* d_ws, size_t ws_size,
                              hipStream_t stream) {
    (void)in_sizes; (void)n_in; (void)out_size; (void)ws_size;
    const float* inputs  = (const float*)d_in[0];
    const float* targets = (const float*)d_in[1];
    const float* Wx = (const float*)d_in[2];
    const float* Wu = (const float*)d_in[3];
    const float* W1 = (const float*)d_in[4];
    const float* b1 = (const float*)d_in[5];
    const float* W2 = (const float*)d_in[6];
    const float* b2 = (const float*)d_in[7];
    float* out = (float*)d_out;
    float* v   = (float*)d_ws;  // needs CC*6*BB*4 = 12.6 MB of workspace

    dim3 blk(256);
    dim3 g1(BB / 256, CC);
    hipLaunchKernelGGL(k_phase1, g1, blk, 0, stream, targets, Wx, Wu, v);
    hipLaunchKernelGGL(k_phase2, dim3(BB / 256), blk, 0, stream, Wx, v);
    dim3 g3(BB / 128, CC);
    hipLaunchKernelGGL(k_phase3, g3, blk, 0, stream,
                       inputs, targets, Wx, Wu, W1, b1, W2, b2, v, out);
}